// Round 1
// 649.230 us; speedup vs baseline: 1.0544x; 1.0544x over previous
//
#include <hip/hip_runtime.h>

#define BATCH 8
#define CH 128
#define NPIX 65536
#define PN 1024   // path_num
// psq = 64, channel = 128

// ---------------- K0: precompute M = Wq^T Wk, wqbk = Wq^T bk, wkbq = Wk^T bq, c0 = bq.bk
__global__ __launch_bounds__(256) void k0_precompute(
    const float* __restrict__ Wq, const float* __restrict__ bq,
    const float* __restrict__ Wk, const float* __restrict__ bk,
    float* __restrict__ M, float* __restrict__ wqbk,
    float* __restrict__ wkbq, float* __restrict__ c0) {
  int t = blockIdx.x * 256 + threadIdx.x;
  if (t < 16384) {
    int c = t >> 7, c2 = t & 127;
    float s = 0.f;
    for (int o = 0; o < 128; ++o) s += Wq[o * 128 + c] * Wk[o * 128 + c2];
    M[t] = s;
  } else if (t < 16512) {
    int c = t - 16384;
    float s = 0.f;
    for (int o = 0; o < 128; ++o) s += Wq[o * 128 + c] * bk[o];
    wqbk[c] = s;
  } else if (t < 16640) {
    int c = t - 16512;
    float s = 0.f;
    for (int o = 0; o < 128; ++o) s += bq[o] * Wk[o * 128 + c];
    wkbq[c] = s;
  } else if (t == 16640) {
    float s = 0.f;
    for (int o = 0; o < 128; ++o) s += bq[o] * bk[o];
    c0[0] = s;
  }
}

// ---------------- K1: channel mean+max, scatter into Hilbert/feat layout
__global__ __launch_bounds__(256) void k1_reduce_permute(
    const float* __restrict__ x, const int* __restrict__ rehil,
    float* __restrict__ F) {
  const int b = blockIdx.y;
  const int t = blockIdx.x * 256 + threadIdx.x;  // 0..16383
  const int i0 = t * 4;
  const float* xb = x + (size_t)b * CH * NPIX + i0;
  float4 s = make_float4(0.f, 0.f, 0.f, 0.f);
  float4 m = make_float4(-1e30f, -1e30f, -1e30f, -1e30f);
  for (int c = 0; c < CH; ++c) {
    const float4 v = *(const float4*)(xb + (size_t)c * NPIX);
    s.x += v.x; s.y += v.y; s.z += v.z; s.w += v.w;
    m.x = fmaxf(m.x, v.x); m.y = fmaxf(m.y, v.y);
    m.z = fmaxf(m.z, v.z); m.w = fmaxf(m.w, v.w);
  }
  const float inv = 1.f / (float)CH;
  float mean[4] = {s.x * inv, s.y * inv, s.z * inv, s.w * inv};
  float mx[4] = {m.x, m.y, m.z, m.w};
  const int4 d4 = *(const int4*)(rehil + i0);
  int ds[4] = {d4.x, d4.y, d4.z, d4.w};
  float* Fb = F + (size_t)b * CH * PN;
#pragma unroll
  for (int e = 0; e < 4; ++e) {
    int d = ds[e];
    int p = d >> 6, j = d & 63;
    Fb[j * PN + p] = mean[e];
    Fb[(64 + j) * PN + p] = mx[e];
  }
}

// ---------------- K2: C = [M; Wv; wqbk^T; wkbq^T] * F  (260x1024, K=128)
// rows<128 -> G; rows 128..255 -> Vt (+bv); row 256 -> u; row 257 -> v
__global__ __launch_bounds__(256) void k2_gv(
    const float* __restrict__ M, const float* __restrict__ Wv,
    const float* __restrict__ bv, const float* __restrict__ wqbk,
    const float* __restrict__ wkbq, const float* __restrict__ F,
    float* __restrict__ G, float* __restrict__ Vt,
    float* __restrict__ u, float* __restrict__ v) {
  __shared__ float As[16][64];
  __shared__ float Bs[16][64];
  const int b = blockIdx.z;
  const int r0 = blockIdx.y * 64;  // 0,64,128,192,256
  const int q0 = blockIdx.x * 64;
  const float* Fb = F + (size_t)b * CH * PN;
  const int t = threadIdx.x;
  const int tx = t & 15, ty = t >> 4;
  const int arow = t & 63, ak4 = (t >> 6) * 4;
  float acc[4][4] = {};
  for (int k0 = 0; k0 < 128; k0 += 16) {
    const int r = r0 + arow;
    const float* Arow = (r < 128)   ? (M + r * 128)
                        : (r < 256) ? (Wv + (r - 128) * 128)
                        : (r == 256) ? wqbk : wkbq;
    float4 a = *(const float4*)(Arow + k0 + ak4);
    As[ak4 + 0][arow] = a.x;
    As[ak4 + 1][arow] = a.y;
    As[ak4 + 2][arow] = a.z;
    As[ak4 + 3][arow] = a.w;
    *(float4*)&Bs[ty][tx * 4] =
        *(const float4*)(Fb + (size_t)(k0 + ty) * PN + q0 + tx * 4);
    __syncthreads();
#pragma unroll
    for (int kk = 0; kk < 16; ++kk) {
      float4 a4 = *(const float4*)&As[kk][ty * 4];
      float4 b4 = *(const float4*)&Bs[kk][tx * 4];
      float av[4] = {a4.x, a4.y, a4.z, a4.w};
      float bw[4] = {b4.x, b4.y, b4.z, b4.w};
#pragma unroll
      for (int i = 0; i < 4; ++i)
#pragma unroll
        for (int j = 0; j < 4; ++j) acc[i][j] = fmaf(av[i], bw[j], acc[i][j]);
    }
    __syncthreads();
  }
  float* Gb = G + (size_t)b * CH * PN;
  float* Vtb = Vt + (size_t)b * PN * CH;
#pragma unroll
  for (int i = 0; i < 4; ++i) {
    const int r = r0 + ty * 4 + i;
#pragma unroll
    for (int j = 0; j < 4; ++j) {
      const int q = q0 + tx * 4 + j;
      if (r < 128) Gb[r * PN + q] = acc[i][j];
      else if (r < 256) Vtb[(size_t)q * CH + (r - 128)] = acc[i][j] + bv[r - 128];
      else if (r == 256) u[b * PN + q] = acc[i][j];
      else if (r == 257) v[b * PN + q] = acc[i][j];
    }
  }
}

// ---------------- K3: St[b][q][p] = sum_k G[k][q]*F[k][p] + u[p] + v[q] + c0
// plus per-(q, p-tile) partial softmax stats: Pm = tile max over p, Pz = sum exp(s - Pm)
__global__ __launch_bounds__(256) void k3_scores(
    const float* __restrict__ G, const float* __restrict__ F,
    const float* __restrict__ u, const float* __restrict__ v,
    const float* __restrict__ c0, float* __restrict__ St,
    float* __restrict__ Pm, float* __restrict__ Pz) {
  __shared__ float As[16][64];  // G[k][q-tile]
  __shared__ float Bs[16][64];  // F[k][p-tile]
  const int b = blockIdx.z;
  const int q0 = blockIdx.y * 64;
  const int p0 = blockIdx.x * 64;
  const float* Gb = G + (size_t)b * CH * PN;
  const float* Fb = F + (size_t)b * CH * PN;
  const int t = threadIdx.x;
  const int tx = t & 15, ty = t >> 4;
  float acc[4][4] = {};
  for (int k0 = 0; k0 < 128; k0 += 16) {
    *(float4*)&As[ty][tx * 4] =
        *(const float4*)(Gb + (size_t)(k0 + ty) * PN + q0 + tx * 4);
    *(float4*)&Bs[ty][tx * 4] =
        *(const float4*)(Fb + (size_t)(k0 + ty) * PN + p0 + tx * 4);
    __syncthreads();
#pragma unroll
    for (int kk = 0; kk < 16; ++kk) {
      float4 a4 = *(const float4*)&As[kk][ty * 4];
      float4 b4 = *(const float4*)&Bs[kk][tx * 4];
      float av[4] = {a4.x, a4.y, a4.z, a4.w};
      float bw[4] = {b4.x, b4.y, b4.z, b4.w};
#pragma unroll
      for (int i = 0; i < 4; ++i)
#pragma unroll
        for (int j = 0; j < 4; ++j) acc[i][j] = fmaf(av[i], bw[j], acc[i][j]);
    }
    __syncthreads();
  }
  const float cc = c0[0];
  const float4 up = *(const float4*)(u + b * PN + p0 + tx * 4);
  const float uv[4] = {up.x, up.y, up.z, up.w};
  float* Sb = St + (size_t)b * PN * PN;
  float* Pmb = Pm + ((size_t)b * 16 + blockIdx.x) * PN;
  float* Pzb = Pz + ((size_t)b * 16 + blockIdx.x) * PN;
#pragma unroll
  for (int i = 0; i < 4; ++i) {
    const int q = q0 + ty * 4 + i;
    const float vq = v[b * PN + q] + cc;
    float s[4];
#pragma unroll
    for (int j = 0; j < 4; ++j) s[j] = acc[i][j] + uv[j] + vq;
    *(float4*)(Sb + (size_t)q * PN + p0 + tx * 4) =
        make_float4(s[0], s[1], s[2], s[3]);
    // per-row (q) tile reduction over p: across 4 j's and 16 tx lanes
    float rm = fmaxf(fmaxf(s[0], s[1]), fmaxf(s[2], s[3]));
#pragma unroll
    for (int off = 1; off <= 8; off <<= 1) rm = fmaxf(rm, __shfl_xor(rm, off));
    float z = __expf(s[0] - rm) + __expf(s[1] - rm) +
              __expf(s[2] - rm) + __expf(s[3] - rm);
#pragma unroll
    for (int off = 1; off <= 8; off <<= 1) z += __shfl_xor(z, off);
    if (tx == 0) { Pmb[q] = rm; Pzb[q] = z; }
  }
}

// ---------------- K4b: combine 16 tile partials -> m[q], invZ[q]
__global__ __launch_bounds__(256) void k4_combine(
    const float* __restrict__ Pm, const float* __restrict__ Pz,
    float* __restrict__ mOut, float* __restrict__ izOut) {
  const int row = blockIdx.x * 256 + threadIdx.x;  // b*1024+q, 0..8191
  const int b = row >> 10, q = row & 1023;
  const float* Pmb = Pm + (size_t)b * 16 * PN + q;
  const float* Pzb = Pz + (size_t)b * 16 * PN + q;
  float m = -1e30f;
#pragma unroll
  for (int ti = 0; ti < 16; ++ti) m = fmaxf(m, Pmb[(size_t)ti * PN]);
  float z = 0.f;
#pragma unroll
  for (int ti = 0; ti < 16; ++ti)
    z += Pzb[(size_t)ti * PN] * __expf(Pmb[(size_t)ti * PN] - m);
  mOut[row] = m;
  izOut[row] = 1.f / z;
}

// ---------------- K5: X3p[qc][b][c][p] = sum_{q in chunk} Vt[q][c]*exp(St[q][p]-m[q])*iz[q]
// full 128 channels per block (St read once); reg-staged LDS double-buffer.
#define QCHUNK 256
__global__ __launch_bounds__(256) void k5_av(
    const float* __restrict__ Vt, const float* __restrict__ St,
    const float* __restrict__ mIn, const float* __restrict__ izIn,
    float* __restrict__ X3p) {
  __shared__ float As[2][16][128];  // Vt[q][c]
  __shared__ float Bs[2][16][64];   // E[q][p-tile]
  const int b = blockIdx.z;
  const int qc = blockIdx.y;
  const int p0 = blockIdx.x * 64;
  const int qbase = qc * QCHUNK;
  const float* Vtb = Vt + (size_t)b * PN * CH;
  const float* Sb = St + (size_t)b * PN * PN;
  const int t = threadIdx.x;
  const int tx = t & 15, ty = t >> 4;

  float4 a0, a1, s0;
  float mq, zq;
  auto issue = [&](int it) {
    const int q = qbase + it * 16 + ty;
    const float* ar = Vtb + (size_t)q * CH + tx * 4;
    a0 = *(const float4*)(ar);
    a1 = *(const float4*)(ar + 64);
    s0 = *(const float4*)(Sb + (size_t)q * PN + p0 + tx * 4);
    mq = mIn[b * PN + q];
    zq = izIn[b * PN + q];
  };
  auto commit = [&](int buf) {
    *(float4*)&As[buf][ty][tx * 4] = a0;
    *(float4*)&As[buf][ty][64 + tx * 4] = a1;
    float4 ev;
    ev.x = __expf(s0.x - mq) * zq;
    ev.y = __expf(s0.y - mq) * zq;
    ev.z = __expf(s0.z - mq) * zq;
    ev.w = __expf(s0.w - mq) * zq;
    *(float4*)&Bs[buf][ty][tx * 4] = ev;
  };

  float acc[8][4] = {};
  issue(0);
  commit(0);
  __syncthreads();
  const int NIT = QCHUNK / 16;  // 16
  for (int it = 0; it < NIT; ++it) {
    const int cur = it & 1;
    if (it + 1 < NIT) issue(it + 1);
#pragma unroll
    for (int kk = 0; kk < 16; ++kk) {
      float4 A0 = *(const float4*)&As[cur][kk][ty * 8];
      float4 A1 = *(const float4*)&As[cur][kk][ty * 8 + 4];
      float4 B0 = *(const float4*)&Bs[cur][kk][tx * 4];
      float av[8] = {A0.x, A0.y, A0.z, A0.w, A1.x, A1.y, A1.z, A1.w};
      float bw[4] = {B0.x, B0.y, B0.z, B0.w};
#pragma unroll
      for (int i = 0; i < 8; ++i)
#pragma unroll
        for (int j = 0; j < 4; ++j) acc[i][j] = fmaf(av[i], bw[j], acc[i][j]);
    }
    if (it + 1 < NIT) commit(cur ^ 1);
    __syncthreads();
  }
  float* X3b = X3p + ((size_t)qc * BATCH + b) * CH * PN;
#pragma unroll
  for (int i = 0; i < 8; ++i) {
    const int c = ty * 8 + i;
    *(float4*)(X3b + (size_t)c * PN + p0 + tx * 4) =
        make_float4(acc[i][0], acc[i][1], acc[i][2], acc[i][3]);
  }
}

// ---------------- K6: X3 = sum of 4 q-chunk partials
__global__ __launch_bounds__(256) void k6_reduce(
    const float* __restrict__ X3p, float* __restrict__ X3) {
  const size_t SZ = (size_t)BATCH * CH * PN;
  const size_t i = ((size_t)blockIdx.x * 256 + threadIdx.x) * 4;
  float4 s0 = *(const float4*)(X3p + i);
  float4 s1 = *(const float4*)(X3p + SZ + i);
  float4 s2 = *(const float4*)(X3p + 2 * SZ + i);
  float4 s3 = *(const float4*)(X3p + 3 * SZ + i);
  float4 o;
  o.x = s0.x + s1.x + s2.x + s3.x;
  o.y = s0.y + s1.y + s2.y + s3.y;
  o.z = s0.z + s1.z + s2.z + s3.z;
  o.w = s0.w + s1.w + s2.w + s3.w;
  *(float4*)(X3 + i) = o;
}

// ---------------- K7: gate = sigmoid(w0*x3c[j][p] + w1*x3c[64+j][p] + bpre); out = gate*x
__global__ __launch_bounds__(256) void k7_out(
    const float* __restrict__ x, const int* __restrict__ rehil,
    const float* __restrict__ X3, const float* __restrict__ Wpre,
    const float* __restrict__ bpre, float* __restrict__ out) {
  const int b = blockIdx.y;
  const int t = blockIdx.x * 256 + threadIdx.x;  // 0..16383
  const int i0 = t * 4;
  const float w0 = Wpre[0], w1 = Wpre[1], b0 = bpre[0];
  const int4 d4 = *(const int4*)(rehil + i0);
  const float* X3b = X3 + (size_t)b * CH * PN;
  int ds[4] = {d4.x, d4.y, d4.z, d4.w};
  float g[4];
#pragma unroll
  for (int e = 0; e < 4; ++e) {
    const int d = ds[e];
    const int p = d >> 6, j = d & 63;
    const float r0v = X3b[j * PN + p];
    const float r1v = X3b[(64 + j) * PN + p];
    const float logit = fmaf(w0, r0v, fmaf(w1, r1v, b0));
    g[e] = 1.f / (1.f + __expf(-logit));
  }
  const size_t base = (size_t)b * CH * NPIX + i0;
#pragma unroll 4
  for (int c = 0; c < CH; ++c) {
    const float4 v = *(const float4*)(x + base + (size_t)c * NPIX);
    float4 o;
    o.x = v.x * g[0];
    o.y = v.y * g[1];
    o.z = v.z * g[2];
    o.w = v.w * g[3];
    *(float4*)(out + base + (size_t)c * NPIX) = o;
  }
}

extern "C" void kernel_launch(void* const* d_in, const int* in_sizes, int n_in,
                              void* d_out, int out_size, void* d_ws,
                              size_t ws_size, hipStream_t stream) {
  const float* x = (const float*)d_in[0];
  const float* Wq = (const float*)d_in[1];
  const float* bq = (const float*)d_in[2];
  const float* Wk = (const float*)d_in[3];
  const float* bk = (const float*)d_in[4];
  const float* Wv = (const float*)d_in[5];
  const float* bv = (const float*)d_in[6];
  const float* Wpre = (const float*)d_in[7];
  const float* bpre = (const float*)d_in[8];
  const int* rehil = (const int*)d_in[10];
  float* out = (float*)d_out;
  float* ws = (float*)d_ws;

  // workspace layout (floats)
  const size_t SZ_FEAT = (size_t)BATCH * CH * PN;  // 1,048,576
  float* F = ws;
  float* G = F + SZ_FEAT;
  float* Vt = G + SZ_FEAT;
  float* X3 = Vt + SZ_FEAT;
  float* X3p = X3 + SZ_FEAT;          // 4 * SZ_FEAT
  float* Mw = X3p + 4 * SZ_FEAT;      // 16384
  float* wqbk = Mw + 16384;           // 128
  float* wkbq = wqbk + 128;           // 128
  float* c0w = wkbq + 128;            // 1 (pad 64)
  float* uw = c0w + 64;               // 8192
  float* vw = uw + 8192;              // 8192
  float* mw = vw + 8192;              // 8192
  float* izw = mw + 8192;             // 8192
  float* Pm = izw + 8192;             // 16*8192 = 131072
  float* Pz = Pm + 16 * 8192;         // 131072
  float* Stw = Pz + 16 * 8192;        // 8,388,608
  const size_t need = (size_t)(Stw - ws) + (size_t)BATCH * PN * PN;
  float* St = Stw;
  if (ws_size < need * sizeof(float)) {
    // fall back: score matrix lives in d_out (32 MB << 268 MB); fully consumed
    // by k5 before k7 overwrites d_out with the real output.
    St = out;
  }

  k0_precompute<<<66, 256, 0, stream>>>(Wq, bq, Wk, bk, Mw, wqbk, wkbq, c0w);
  k1_reduce_permute<<<dim3(64, BATCH), 256, 0, stream>>>(x, rehil, F);
  k2_gv<<<dim3(16, 5, BATCH), 256, 0, stream>>>(Mw, Wv, bv, wqbk, wkbq, F, G,
                                                Vt, uw, vw);
  k3_scores<<<dim3(16, 16, BATCH), 256, 0, stream>>>(G, F, uw, vw, c0w, St, Pm,
                                                     Pz);
  k4_combine<<<32, 256, 0, stream>>>(Pm, Pz, mw, izw);
  k5_av<<<dim3(16, 4, BATCH), 256, 0, stream>>>(Vt, St, mw, izw, X3p);
  k6_reduce<<<1024, 256, 0, stream>>>(X3p, X3);
  k7_out<<<dim3(64, BATCH), 256, 0, stream>>>(x, rehil, X3, Wpre, bpre, out);
}